// Round 1
// baseline (767.622 us; speedup 1.0000x reference)
//
#include <hip/hip_runtime.h>
#include <math.h>

#define N_NODES 50000
#define N_EDGES 800000
#define FDIM 128
#define KCLS 10

// ---------------- CSR build ----------------

__global__ void k_count(const int* __restrict__ dst, int* __restrict__ indeg, int e_total) {
    int e = blockIdx.x * 256 + threadIdx.x;
    if (e < e_total) atomicAdd(&indeg[dst[e]], 1);
}

__global__ __launch_bounds__(1024) void k_scan_block(const int* __restrict__ in, int* __restrict__ excl,
                                                     int* __restrict__ bsum, int n) {
    __shared__ int sh[1024];
    int t = threadIdx.x;
    int g = blockIdx.x * 1024 + t;
    int v = (g < n) ? in[g] : 0;
    sh[t] = v;
    __syncthreads();
    for (int d = 1; d < 1024; d <<= 1) {
        int x = (t >= d) ? sh[t - d] : 0;
        __syncthreads();
        sh[t] += x;
        __syncthreads();
    }
    if (g < n) excl[g] = sh[t] - v;  // exclusive within block
    if (t == 1023) bsum[blockIdx.x] = sh[t];
}

__global__ void k_scan_small(int* bsum, int nb) {
    if (threadIdx.x == 0 && blockIdx.x == 0) {
        int run = 0;
        for (int i = 0; i < nb; i++) { int v = bsum[i]; bsum[i] = run; run += v; }
    }
}

__global__ __launch_bounds__(1024) void k_scan_add(int* __restrict__ offs, const int* __restrict__ bsum,
                                                   int* __restrict__ cursor, int n, int e_total) {
    int g = blockIdx.x * 1024 + threadIdx.x;
    if (g < n) {
        int v = offs[g] + bsum[blockIdx.x];
        offs[g] = v;
        cursor[g] = v;
    }
    if (g == 0) offs[n] = e_total;
}

__global__ void k_scatter(const int* __restrict__ src, const int* __restrict__ dst,
                          int* __restrict__ cursor, int* __restrict__ seid, int* __restrict__ ssrc, int e_total) {
    int e = blockIdx.x * 256 + threadIdx.x;
    if (e < e_total) {
        int d = dst[e];
        int p = atomicAdd(&cursor[d], 1);
        seid[p] = e;
        ssrc[p] = src[e];
    }
}

// ---------------- h = x @ Wp + bp  ([N,64]@[64,128]) ----------------

__global__ __launch_bounds__(256) void k_proj(const float* __restrict__ x, const float* __restrict__ Wp,
                                              const float* __restrict__ bp, float* __restrict__ h, int n) {
    __shared__ float shx[32 * 64];    // 8 KB
    __shared__ float shw[64 * 128];   // 32 KB
    int t = threadIdx.x;
    int row0 = blockIdx.x * 32;
    int nrows = min(32, n - row0);

    for (int i = t; i < 64 * 128 / 4; i += 256)
        ((float4*)shw)[i] = ((const float4*)Wp)[i];
    for (int i = t; i < 32 * 64 / 4; i += 256) {
        int r = i >> 4;  // 16 float4 per row
        float4 v = make_float4(0.f, 0.f, 0.f, 0.f);
        if (r < nrows) v = ((const float4*)x)[row0 * 16 + i];
        ((float4*)shx)[i] = v;
    }
    __syncthreads();

    int tr = (t >> 5) * 4;
    int tc = (t & 31) * 4;
    float acc[4][4];
    float4 b4 = *(const float4*)&bp[tc];
#pragma unroll
    for (int j = 0; j < 4; j++) { acc[j][0] = b4.x; acc[j][1] = b4.y; acc[j][2] = b4.z; acc[j][3] = b4.w; }

    for (int k = 0; k < 64; k++) {
        float4 w = *(float4*)&shw[k * 128 + tc];
#pragma unroll
        for (int j = 0; j < 4; j++) {
            float a = shx[(tr + j) * 64 + k];
            acc[j][0] = fmaf(a, w.x, acc[j][0]);
            acc[j][1] = fmaf(a, w.y, acc[j][1]);
            acc[j][2] = fmaf(a, w.z, acc[j][2]);
            acc[j][3] = fmaf(a, w.w, acc[j][3]);
        }
    }
#pragma unroll
    for (int j = 0; j < 4; j++) {
        int r = row0 + tr + j;
        if (r < n) {
            float4 o = make_float4(acc[j][0], acc[j][1], acc[j][2], acc[j][3]);
            *(float4*)&h[r * 128 + tc] = o;
        }
    }
}

// ---------------- fused LayerNorm + dual GEMM: xl = LN(h)@Wl + bl, xr = LN(h)@Wr + br ----------------

__global__ __launch_bounds__(256) void k_ln_gemm(const float* __restrict__ h,
                                                 const float* __restrict__ lng, const float* __restrict__ lnb,
                                                 const float* __restrict__ Wl, const float* __restrict__ bl,
                                                 const float* __restrict__ Wr, const float* __restrict__ br,
                                                 float* __restrict__ xl, float* __restrict__ xr, int n) {
    __shared__ float shn[32 * 128];   // 16 KB normalized tile
    __shared__ float shwl[32 * 128];  // 16 KB k-chunk of Wl
    __shared__ float shwr[32 * 128];  // 16 KB k-chunk of Wr
    __shared__ float smu[32], srs[32];
    int t = threadIdx.x;
    int row0 = blockIdx.x * 32;
    int nrows = min(32, n - row0);

    // load h tile (contiguous 4096 floats)
    for (int i = t; i < 1024; i += 256) {
        int r = i >> 5;  // 32 float4 per row
        float4 v = make_float4(0.f, 0.f, 0.f, 0.f);
        if (r < nrows) v = ((const float4*)h)[row0 * 32 + i];
        ((float4*)shn)[i] = v;
    }
    __syncthreads();

    // LN stats: 8 lanes per row
    {
        int r = t >> 3, sl = t & 7;
        float s = 0.f, ss = 0.f;
        for (int c = sl; c < 128; c += 8) {
            float v = shn[r * 128 + c];
            s += v; ss += v * v;
        }
#pragma unroll
        for (int o = 1; o < 8; o <<= 1) { s += __shfl_xor(s, o, 64); ss += __shfl_xor(ss, o, 64); }
        if (sl == 0) {
            float mu = s * (1.f / 128.f);
            float var = ss * (1.f / 128.f) - mu * mu;
            smu[r] = mu;
            srs[r] = rsqrtf(var + 1e-5f);
        }
    }
    __syncthreads();
    for (int i = t; i < 4096; i += 256) {
        int r = i >> 7, c = i & 127;
        shn[i] = (shn[i] - smu[r]) * srs[r] * lng[c] + lnb[c];
    }

    int tr = (t >> 5) * 4;
    int tc = (t & 31) * 4;
    float accl[4][4], accr[4][4];
    {
        float4 bl4 = *(const float4*)&bl[tc];
        float4 br4 = *(const float4*)&br[tc];
#pragma unroll
        for (int j = 0; j < 4; j++) {
            accl[j][0] = bl4.x; accl[j][1] = bl4.y; accl[j][2] = bl4.z; accl[j][3] = bl4.w;
            accr[j][0] = br4.x; accr[j][1] = br4.y; accr[j][2] = br4.z; accr[j][3] = br4.w;
        }
    }

    for (int kb = 0; kb < 4; kb++) {
        __syncthreads();
        for (int i = t; i < 1024; i += 256) {
            ((float4*)shwl)[i] = ((const float4*)Wl)[kb * 1024 + i];
            ((float4*)shwr)[i] = ((const float4*)Wr)[kb * 1024 + i];
        }
        __syncthreads();
#pragma unroll 8
        for (int kk = 0; kk < 32; kk++) {
            int k = kb * 32 + kk;
            float4 wl4 = *(float4*)&shwl[kk * 128 + tc];
            float4 wr4 = *(float4*)&shwr[kk * 128 + tc];
#pragma unroll
            for (int j = 0; j < 4; j++) {
                float a = shn[(tr + j) * 128 + k];
                accl[j][0] = fmaf(a, wl4.x, accl[j][0]);
                accl[j][1] = fmaf(a, wl4.y, accl[j][1]);
                accl[j][2] = fmaf(a, wl4.z, accl[j][2]);
                accl[j][3] = fmaf(a, wl4.w, accl[j][3]);
                accr[j][0] = fmaf(a, wr4.x, accr[j][0]);
                accr[j][1] = fmaf(a, wr4.y, accr[j][1]);
                accr[j][2] = fmaf(a, wr4.z, accr[j][2]);
                accr[j][3] = fmaf(a, wr4.w, accr[j][3]);
            }
        }
    }
#pragma unroll
    for (int j = 0; j < 4; j++) {
        int r = row0 + tr + j;
        if (r < n) {
            float4 ol = make_float4(accl[j][0], accl[j][1], accl[j][2], accl[j][3]);
            float4 orr = make_float4(accr[j][0], accr[j][1], accr[j][2], accr[j][3]);
            *(float4*)&xl[r * 128 + tc] = ol;
            *(float4*)&xr[r * 128 + tc] = orr;
        }
    }
}

// ---------------- GAT aggregate: one wave per node, online softmax over in-edges ----------------

__global__ __launch_bounds__(256) void k_gat_agg(const float* __restrict__ xl, const float* __restrict__ xr,
                                                 const float* __restrict__ edge_attr,
                                                 const int* __restrict__ offs,
                                                 const int* __restrict__ seid, const int* __restrict__ ssrc,
                                                 const float* __restrict__ We, const float* __restrict__ att,
                                                 const float* __restrict__ bout, float* __restrict__ h, int n) {
    int wid = threadIdx.x >> 6;
    int lane = threadIdx.x & 63;
    int node = blockIdx.x * 4 + wid;
    if (node >= n) return;

    float we0[16], we1[16];
#pragma unroll
    for (int k = 0; k < 16; k++) {
        we0[k] = We[k * 128 + lane];
        we1[k] = We[k * 128 + 64 + lane];
    }
    float a0 = att[lane], a1 = att[64 + lane];
    float xr0 = xr[node * 128 + lane];
    float xr1 = xr[node * 128 + 64 + lane];

    int s = offs[node], e = offs[node + 1];
    float m0 = -INFINITY, m1 = -INFINITY;
    float s0 = 0.f, s1 = 0.f;
    float A0 = 0.f, A1 = 0.f;

    for (int j = s; j < e; j++) {
        int eid = seid[j];
        int sn = ssrc[j];
        float ea = (lane < 16) ? edge_attr[eid * 16 + lane] : 0.f;
        float xls0 = xl[sn * 128 + lane];
        float xls1 = xl[sn * 128 + 64 + lane];
        float ee0 = 0.f, ee1 = 0.f;
#pragma unroll
        for (int k = 0; k < 16; k++) {
            float c = __shfl(ea, k, 64);
            ee0 = fmaf(c, we0[k], ee0);
            ee1 = fmaf(c, we1[k], ee1);
        }
        float v0 = xls0 + xr0 + ee0; v0 = v0 > 0.f ? v0 : 0.2f * v0;
        float v1 = xls1 + xr1 + ee1; v1 = v1 > 0.f ? v1 : 0.2f * v1;
        float p = v0 * a0, q = v1 * a1;
#pragma unroll
        for (int o = 32; o; o >>= 1) { p += __shfl_xor(p, o, 64); q += __shfl_xor(q, o, 64); }
        // online softmax, head 0
        float nm0 = fmaxf(m0, p);
        float sc0 = __expf(m0 - nm0);
        float w0 = __expf(p - nm0);
        s0 = s0 * sc0 + w0;
        A0 = fmaf(w0, xls0, A0 * sc0);
        m0 = nm0;
        // head 1
        float nm1 = fmaxf(m1, q);
        float sc1 = __expf(m1 - nm1);
        float w1 = __expf(q - nm1);
        s1 = s1 * sc1 + w1;
        A1 = fmaf(w1, xls1, A1 * sc1);
        m1 = nm1;
    }

    float o0 = (e > s) ? (A0 / s0) : 0.f;
    float o1 = (e > s) ? (A1 / s1) : 0.f;
    float hg0 = o0 + bout[lane];
    float hg1 = o1 + bout[64 + lane];
    int b0 = node * 128 + lane;
    h[b0] = fmaxf(hg0, 0.f) + h[b0];
    h[b0 + 64] = fmaxf(hg1, 0.f) + h[b0 + 64];
}

// ---------------- classifier + embedding write ----------------

__global__ __launch_bounds__(256) void k_cls(const float* __restrict__ h, const float* __restrict__ Wc,
                                             const float* __restrict__ bc,
                                             float* __restrict__ out_cls, float* __restrict__ out_emb, int n) {
    int wid = threadIdx.x >> 6;
    int lane = threadIdx.x & 63;
    int node = blockIdx.x * 4 + wid;
    if (node >= n) return;
    float h0 = h[node * 128 + lane];
    float h1 = h[node * 128 + 64 + lane];
    float p0 = h0 * Wc[lane * 10 + 0] + h1 * Wc[(64 + lane) * 10 + 0];
    float p1 = h0 * Wc[lane * 10 + 1] + h1 * Wc[(64 + lane) * 10 + 1];
    float p2 = h0 * Wc[lane * 10 + 2] + h1 * Wc[(64 + lane) * 10 + 2];
    float p3 = h0 * Wc[lane * 10 + 3] + h1 * Wc[(64 + lane) * 10 + 3];
    float p4 = h0 * Wc[lane * 10 + 4] + h1 * Wc[(64 + lane) * 10 + 4];
    float p5 = h0 * Wc[lane * 10 + 5] + h1 * Wc[(64 + lane) * 10 + 5];
    float p6 = h0 * Wc[lane * 10 + 6] + h1 * Wc[(64 + lane) * 10 + 6];
    float p7 = h0 * Wc[lane * 10 + 7] + h1 * Wc[(64 + lane) * 10 + 7];
    float p8 = h0 * Wc[lane * 10 + 8] + h1 * Wc[(64 + lane) * 10 + 8];
    float p9 = h0 * Wc[lane * 10 + 9] + h1 * Wc[(64 + lane) * 10 + 9];
#pragma unroll
    for (int o = 32; o; o >>= 1) {
        p0 += __shfl_xor(p0, o, 64); p1 += __shfl_xor(p1, o, 64);
        p2 += __shfl_xor(p2, o, 64); p3 += __shfl_xor(p3, o, 64);
        p4 += __shfl_xor(p4, o, 64); p5 += __shfl_xor(p5, o, 64);
        p6 += __shfl_xor(p6, o, 64); p7 += __shfl_xor(p7, o, 64);
        p8 += __shfl_xor(p8, o, 64); p9 += __shfl_xor(p9, o, 64);
    }
    if (lane == 0) {
        out_cls[node * 10 + 0] = p0 + bc[0];
        out_cls[node * 10 + 1] = p1 + bc[1];
        out_cls[node * 10 + 2] = p2 + bc[2];
        out_cls[node * 10 + 3] = p3 + bc[3];
        out_cls[node * 10 + 4] = p4 + bc[4];
        out_cls[node * 10 + 5] = p5 + bc[5];
        out_cls[node * 10 + 6] = p6 + bc[6];
        out_cls[node * 10 + 7] = p7 + bc[7];
        out_cls[node * 10 + 8] = p8 + bc[8];
        out_cls[node * 10 + 9] = p9 + bc[9];
    }
    out_emb[node * 128 + lane] = h0;
    out_emb[node * 128 + 64 + lane] = h1;
}

extern "C" void kernel_launch(void* const* d_in, const int* in_sizes, int n_in,
                              void* d_out, int out_size, void* d_ws, size_t ws_size,
                              hipStream_t stream) {
    const float* x         = (const float*)d_in[0];
    const int*   edge_idx  = (const int*)d_in[1];
    const float* edge_attr = (const float*)d_in[2];
    const float* Wp        = (const float*)d_in[3];
    const float* bp        = (const float*)d_in[4];
    const float* lng       = (const float*)d_in[5];
    const float* lnb       = (const float*)d_in[6];
    const float* Wl        = (const float*)d_in[7];
    const float* bl        = (const float*)d_in[8];
    const float* Wr        = (const float*)d_in[9];
    const float* br        = (const float*)d_in[10];
    const float* We        = (const float*)d_in[11];
    const float* att       = (const float*)d_in[12];
    const float* bout      = (const float*)d_in[13];
    const float* Wc        = (const float*)d_in[14];
    const float* bc        = (const float*)d_in[15];

    const int N = N_NODES, E = N_EDGES;

    // workspace carve
    char* w = (char*)d_ws;
    auto take = [&](size_t bytes) -> void* {
        void* p = (void*)w;
        w += (bytes + 255) & ~(size_t)255;
        return p;
    };
    float* h      = (float*)take((size_t)N * 128 * 4);
    float* xl     = (float*)take((size_t)N * 128 * 4);
    float* xr     = (float*)take((size_t)N * 128 * 4);
    int*   indeg  = (int*)take((size_t)N * 4);
    int*   offs   = (int*)take((size_t)(N + 1) * 4);
    int*   cursor = (int*)take((size_t)N * 4);
    int*   bsum   = (int*)take(64 * 4);
    int*   seid   = (int*)take((size_t)E * 4);
    int*   ssrc   = (int*)take((size_t)E * 4);

    const int* srcArr = edge_idx;       // edge_index[0]
    const int* dstArr = edge_idx + E;   // edge_index[1]

    // CSR build (per call; edge_index is constant input)
    hipMemsetAsync(indeg, 0, (size_t)N * 4, stream);
    k_count<<<(E + 255) / 256, 256, 0, stream>>>(dstArr, indeg, E);
    int NB = (N + 1023) / 1024;  // 49
    k_scan_block<<<NB, 1024, 0, stream>>>(indeg, offs, bsum, N);
    k_scan_small<<<1, 64, 0, stream>>>(bsum, NB);
    k_scan_add<<<NB, 1024, 0, stream>>>(offs, bsum, cursor, N, E);
    k_scatter<<<(E + 255) / 256, 256, 0, stream>>>(srcArr, dstArr, cursor, seid, ssrc, E);

    // node projection
    k_proj<<<(N + 31) / 32, 256, 0, stream>>>(x, Wp, bp, h, N);

    for (int i = 0; i < 2; i++) {
        k_ln_gemm<<<(N + 31) / 32, 256, 0, stream>>>(
            h, lng + i * 128, lnb + i * 128,
            Wl + (size_t)i * 128 * 128, bl + i * 128,
            Wr + (size_t)i * 128 * 128, br + i * 128,
            xl, xr, N);
        k_gat_agg<<<(N + 3) / 4, 256, 0, stream>>>(
            xl, xr, edge_attr, offs, seid, ssrc,
            We + (size_t)i * 16 * 128, att + i * 128, bout + i * 128, h, N);
    }

    k_cls<<<(N + 3) / 4, 256, 0, stream>>>(h, Wc, bc, (float*)d_out, (float*)d_out + (size_t)N * KCLS, N);
}

// Round 2
// 643.803 us; speedup vs baseline: 1.1923x; 1.1923x over previous
//
#include <hip/hip_runtime.h>
#include <math.h>

#define N_NODES 50000
#define N_EDGES 800000
#define FDIM 128
#define KCLS 10

// ---------------- CSR build ----------------

__global__ void k_count(const int* __restrict__ dst, int* __restrict__ indeg, int e_total) {
    int e = blockIdx.x * 256 + threadIdx.x;
    if (e < e_total) atomicAdd(&indeg[dst[e]], 1);
}

__global__ __launch_bounds__(1024) void k_scan_block(const int* __restrict__ in, int* __restrict__ excl,
                                                     int* __restrict__ bsum, int n) {
    __shared__ int sh[1024];
    int t = threadIdx.x;
    int g = blockIdx.x * 1024 + t;
    int v = (g < n) ? in[g] : 0;
    sh[t] = v;
    __syncthreads();
    for (int d = 1; d < 1024; d <<= 1) {
        int x = (t >= d) ? sh[t - d] : 0;
        __syncthreads();
        sh[t] += x;
        __syncthreads();
    }
    if (g < n) excl[g] = sh[t] - v;  // exclusive within block
    if (t == 1023) bsum[blockIdx.x] = sh[t];
}

__global__ void k_scan_small(int* bsum, int nb) {
    if (threadIdx.x == 0 && blockIdx.x == 0) {
        int run = 0;
        for (int i = 0; i < nb; i++) { int v = bsum[i]; bsum[i] = run; run += v; }
    }
}

__global__ __launch_bounds__(1024) void k_scan_add(int* __restrict__ offs, const int* __restrict__ bsum,
                                                   int* __restrict__ cursor, int n, int e_total) {
    int g = blockIdx.x * 1024 + threadIdx.x;
    if (g < n) {
        int v = offs[g] + bsum[blockIdx.x];
        offs[g] = v;
        cursor[g] = v;
    }
    if (g == 0) offs[n] = e_total;
}

__global__ void k_scatter(const int* __restrict__ src, const int* __restrict__ dst,
                          int* __restrict__ cursor, int* __restrict__ seid, int* __restrict__ ssrc, int e_total) {
    int e = blockIdx.x * 256 + threadIdx.x;
    if (e < e_total) {
        int d = dst[e];
        int p = atomicAdd(&cursor[d], 1);
        seid[p] = e;
        ssrc[p] = src[e];
    }
}

// copy edge_attr into CSR (sorted) order: coalesced writes, gathered reads
__global__ void k_gather_ea(const int* __restrict__ seid, const float* __restrict__ edge_attr,
                            float* __restrict__ sea, int e_total) {
    int p = blockIdx.x * 256 + threadIdx.x;
    int ep = p >> 2, q = p & 3;
    if (ep < e_total) {
        int eid = seid[ep];
        ((float4*)sea)[ep * 4 + q] = ((const float4*)edge_attr)[eid * 4 + q];
    }
}

// ---------------- h = x @ Wp + bp  ([N,64]@[64,128]) ----------------

__global__ __launch_bounds__(256) void k_proj(const float* __restrict__ x, const float* __restrict__ Wp,
                                              const float* __restrict__ bp, float* __restrict__ h, int n) {
    __shared__ float shx[32 * 64];
    __shared__ float shw[64 * 128];
    int t = threadIdx.x;
    int row0 = blockIdx.x * 32;
    int nrows = min(32, n - row0);

    for (int i = t; i < 64 * 128 / 4; i += 256)
        ((float4*)shw)[i] = ((const float4*)Wp)[i];
    for (int i = t; i < 32 * 64 / 4; i += 256) {
        int r = i >> 4;
        float4 v = make_float4(0.f, 0.f, 0.f, 0.f);
        if (r < nrows) v = ((const float4*)x)[row0 * 16 + i];
        ((float4*)shx)[i] = v;
    }
    __syncthreads();

    int tr = (t >> 5) * 4;
    int tc = (t & 31) * 4;
    float acc[4][4];
    float4 b4 = *(const float4*)&bp[tc];
#pragma unroll
    for (int j = 0; j < 4; j++) { acc[j][0] = b4.x; acc[j][1] = b4.y; acc[j][2] = b4.z; acc[j][3] = b4.w; }

    for (int k = 0; k < 64; k++) {
        float4 w = *(float4*)&shw[k * 128 + tc];
#pragma unroll
        for (int j = 0; j < 4; j++) {
            float a = shx[(tr + j) * 64 + k];
            acc[j][0] = fmaf(a, w.x, acc[j][0]);
            acc[j][1] = fmaf(a, w.y, acc[j][1]);
            acc[j][2] = fmaf(a, w.z, acc[j][2]);
            acc[j][3] = fmaf(a, w.w, acc[j][3]);
        }
    }
#pragma unroll
    for (int j = 0; j < 4; j++) {
        int r = row0 + tr + j;
        if (r < n) {
            float4 o = make_float4(acc[j][0], acc[j][1], acc[j][2], acc[j][3]);
            *(float4*)&h[r * 128 + tc] = o;
        }
    }
}

// ---------------- fused LayerNorm + dual GEMM ----------------

__global__ __launch_bounds__(256) void k_ln_gemm(const float* __restrict__ h,
                                                 const float* __restrict__ lng, const float* __restrict__ lnb,
                                                 const float* __restrict__ Wl, const float* __restrict__ bl,
                                                 const float* __restrict__ Wr, const float* __restrict__ br,
                                                 float* __restrict__ xl, float* __restrict__ xr, int n) {
    __shared__ float shn[32 * 128];
    __shared__ float shwl[32 * 128];
    __shared__ float shwr[32 * 128];
    __shared__ float smu[32], srs[32];
    int t = threadIdx.x;
    int row0 = blockIdx.x * 32;
    int nrows = min(32, n - row0);

    for (int i = t; i < 1024; i += 256) {
        int r = i >> 5;
        float4 v = make_float4(0.f, 0.f, 0.f, 0.f);
        if (r < nrows) v = ((const float4*)h)[row0 * 32 + i];
        ((float4*)shn)[i] = v;
    }
    __syncthreads();

    {
        int r = t >> 3, sl = t & 7;
        float s = 0.f, ss = 0.f;
        for (int c = sl; c < 128; c += 8) {
            float v = shn[r * 128 + c];
            s += v; ss += v * v;
        }
#pragma unroll
        for (int o = 1; o < 8; o <<= 1) { s += __shfl_xor(s, o, 64); ss += __shfl_xor(ss, o, 64); }
        if (sl == 0) {
            float mu = s * (1.f / 128.f);
            float var = ss * (1.f / 128.f) - mu * mu;
            smu[r] = mu;
            srs[r] = rsqrtf(var + 1e-5f);
        }
    }
    __syncthreads();
    for (int i = t; i < 4096; i += 256) {
        int r = i >> 7, c = i & 127;
        shn[i] = (shn[i] - smu[r]) * srs[r] * lng[c] + lnb[c];
    }

    int tr = (t >> 5) * 4;
    int tc = (t & 31) * 4;
    float accl[4][4], accr[4][4];
    {
        float4 bl4 = *(const float4*)&bl[tc];
        float4 br4 = *(const float4*)&br[tc];
#pragma unroll
        for (int j = 0; j < 4; j++) {
            accl[j][0] = bl4.x; accl[j][1] = bl4.y; accl[j][2] = bl4.z; accl[j][3] = bl4.w;
            accr[j][0] = br4.x; accr[j][1] = br4.y; accr[j][2] = br4.z; accr[j][3] = br4.w;
        }
    }

    for (int kb = 0; kb < 4; kb++) {
        __syncthreads();
        for (int i = t; i < 1024; i += 256) {
            ((float4*)shwl)[i] = ((const float4*)Wl)[kb * 1024 + i];
            ((float4*)shwr)[i] = ((const float4*)Wr)[kb * 1024 + i];
        }
        __syncthreads();
#pragma unroll 8
        for (int kk = 0; kk < 32; kk++) {
            int k = kb * 32 + kk;
            float4 wl4 = *(float4*)&shwl[kk * 128 + tc];
            float4 wr4 = *(float4*)&shwr[kk * 128 + tc];
#pragma unroll
            for (int j = 0; j < 4; j++) {
                float a = shn[(tr + j) * 128 + k];
                accl[j][0] = fmaf(a, wl4.x, accl[j][0]);
                accl[j][1] = fmaf(a, wl4.y, accl[j][1]);
                accl[j][2] = fmaf(a, wl4.z, accl[j][2]);
                accl[j][3] = fmaf(a, wl4.w, accl[j][3]);
                accr[j][0] = fmaf(a, wr4.x, accr[j][0]);
                accr[j][1] = fmaf(a, wr4.y, accr[j][1]);
                accr[j][2] = fmaf(a, wr4.z, accr[j][2]);
                accr[j][3] = fmaf(a, wr4.w, accr[j][3]);
            }
        }
    }
#pragma unroll
    for (int j = 0; j < 4; j++) {
        int r = row0 + tr + j;
        if (r < n) {
            float4 ol = make_float4(accl[j][0], accl[j][1], accl[j][2], accl[j][3]);
            float4 orr = make_float4(accr[j][0], accr[j][1], accr[j][2], accr[j][3]);
            *(float4*)&xl[r * 128 + tc] = ol;
            *(float4*)&xr[r * 128 + tc] = orr;
        }
    }
}

// ---------------- GAT aggregate v2 ----------------
// lane = (head, channel-pair): lanes 0-31 head0 (float2 channels), 32-63 head1.
// One shared 5-level butterfly reduces both heads; ee coeffs read as uniform
// float4 VMEM broadcasts (no shfl); edges unrolled x2 with fused softmax merge.

__device__ __forceinline__ void ee16(const float4& c0, const float4& c1, const float4& c2, const float4& c3,
                                     const float2* we, float& e0, float& e1) {
    e0 = fmaf(c0.x, we[0].x, e0);  e1 = fmaf(c0.x, we[0].y, e1);
    e0 = fmaf(c0.y, we[1].x, e0);  e1 = fmaf(c0.y, we[1].y, e1);
    e0 = fmaf(c0.z, we[2].x, e0);  e1 = fmaf(c0.z, we[2].y, e1);
    e0 = fmaf(c0.w, we[3].x, e0);  e1 = fmaf(c0.w, we[3].y, e1);
    e0 = fmaf(c1.x, we[4].x, e0);  e1 = fmaf(c1.x, we[4].y, e1);
    e0 = fmaf(c1.y, we[5].x, e0);  e1 = fmaf(c1.y, we[5].y, e1);
    e0 = fmaf(c1.z, we[6].x, e0);  e1 = fmaf(c1.z, we[6].y, e1);
    e0 = fmaf(c1.w, we[7].x, e0);  e1 = fmaf(c1.w, we[7].y, e1);
    e0 = fmaf(c2.x, we[8].x, e0);  e1 = fmaf(c2.x, we[8].y, e1);
    e0 = fmaf(c2.y, we[9].x, e0);  e1 = fmaf(c2.y, we[9].y, e1);
    e0 = fmaf(c2.z, we[10].x, e0); e1 = fmaf(c2.z, we[10].y, e1);
    e0 = fmaf(c2.w, we[11].x, e0); e1 = fmaf(c2.w, we[11].y, e1);
    e0 = fmaf(c3.x, we[12].x, e0); e1 = fmaf(c3.x, we[12].y, e1);
    e0 = fmaf(c3.y, we[13].x, e0); e1 = fmaf(c3.y, we[13].y, e1);
    e0 = fmaf(c3.z, we[14].x, e0); e1 = fmaf(c3.z, we[14].y, e1);
    e0 = fmaf(c3.w, we[15].x, e0); e1 = fmaf(c3.w, we[15].y, e1);
}

template <bool SORTED>
__global__ __launch_bounds__(256) void k_gat_agg2(const float* __restrict__ xl, const float* __restrict__ xr,
                                                  const float* __restrict__ eattr,  // sea if SORTED else edge_attr
                                                  const int* __restrict__ offs,
                                                  const int* __restrict__ seid, const int* __restrict__ ssrc,
                                                  const float* __restrict__ We, const float* __restrict__ att,
                                                  const float* __restrict__ bout, float* __restrict__ h, int n) {
    int wid = threadIdx.x >> 6;
    int lane = threadIdx.x & 63;
    int node = blockIdx.x * 4 + wid;
    if (node >= n) return;

    int half = lane >> 5;
    int chb = half * 64 + (lane & 31) * 2;

    float2 we[16];
#pragma unroll
    for (int k = 0; k < 16; k++) we[k] = *(const float2*)&We[k * 128 + chb];
    float2 av = *(const float2*)&att[chb];
    float2 xr2 = *(const float2*)&xr[(size_t)node * 128 + chb];
    float2 bo = *(const float2*)&bout[chb];

    int s = offs[node], e = offs[node + 1];
    float m = -INFINITY, den = 0.f;
    float A0 = 0.f, A1 = 0.f;

    int j = s;
    for (; j + 2 <= e; j += 2) {
        int sna = ssrc[j], snb = ssrc[j + 1];
        const float4* eaA = (const float4*)&eattr[(size_t)(SORTED ? j : seid[j]) * 16];
        const float4* eaB = (const float4*)&eattr[(size_t)(SORTED ? (j + 1) : seid[j + 1]) * 16];
        float4 c0 = eaA[0], c1 = eaA[1], c2 = eaA[2], c3 = eaA[3];
        float4 d0 = eaB[0], d1 = eaB[1], d2 = eaB[2], d3 = eaB[3];
        float2 lxa = *(const float2*)&xl[(size_t)sna * 128 + chb];
        float2 lxb = *(const float2*)&xl[(size_t)snb * 128 + chb];

        float ea0 = 0.f, ea1 = 0.f, eb0 = 0.f, eb1 = 0.f;
        ee16(c0, c1, c2, c3, we, ea0, ea1);
        ee16(d0, d1, d2, d3, we, eb0, eb1);

        float va0 = lxa.x + xr2.x + ea0; va0 = va0 > 0.f ? va0 : 0.2f * va0;
        float va1 = lxa.y + xr2.y + ea1; va1 = va1 > 0.f ? va1 : 0.2f * va1;
        float vb0 = lxb.x + xr2.x + eb0; vb0 = vb0 > 0.f ? vb0 : 0.2f * vb0;
        float vb1 = lxb.y + xr2.y + eb1; vb1 = vb1 > 0.f ? vb1 : 0.2f * vb1;
        float pa = va0 * av.x + va1 * av.y;
        float pb = vb0 * av.x + vb1 * av.y;
#pragma unroll
        for (int o = 1; o <= 16; o <<= 1) {
            pa += __shfl_xor(pa, o, 64);
            pb += __shfl_xor(pb, o, 64);
        }
        float nm = fmaxf(m, fmaxf(pa, pb));
        float sc = __expf(m - nm);
        float wa = __expf(pa - nm);
        float wb = __expf(pb - nm);
        den = den * sc + wa + wb;
        A0 = fmaf(wa, lxa.x, fmaf(wb, lxb.x, A0 * sc));
        A1 = fmaf(wa, lxa.y, fmaf(wb, lxb.y, A1 * sc));
        m = nm;
    }
    if (j < e) {
        int sna = ssrc[j];
        const float4* eaA = (const float4*)&eattr[(size_t)(SORTED ? j : seid[j]) * 16];
        float4 c0 = eaA[0], c1 = eaA[1], c2 = eaA[2], c3 = eaA[3];
        float2 lxa = *(const float2*)&xl[(size_t)sna * 128 + chb];
        float ea0 = 0.f, ea1 = 0.f;
        ee16(c0, c1, c2, c3, we, ea0, ea1);
        float va0 = lxa.x + xr2.x + ea0; va0 = va0 > 0.f ? va0 : 0.2f * va0;
        float va1 = lxa.y + xr2.y + ea1; va1 = va1 > 0.f ? va1 : 0.2f * va1;
        float pa = va0 * av.x + va1 * av.y;
#pragma unroll
        for (int o = 1; o <= 16; o <<= 1) pa += __shfl_xor(pa, o, 64);
        float nm = fmaxf(m, pa);
        float sc = __expf(m - nm);
        float wa = __expf(pa - nm);
        den = den * sc + wa;
        A0 = fmaf(wa, lxa.x, A0 * sc);
        A1 = fmaf(wa, lxa.y, A1 * sc);
        m = nm;
    }

    float inv = (e > s) ? (1.f / den) : 0.f;
    float hg0 = fmaxf(fmaf(A0, inv, bo.x), 0.f);
    float hg1 = fmaxf(fmaf(A1, inv, bo.y), 0.f);
    float2* hp = (float2*)&h[(size_t)node * 128 + chb];
    float2 hv = *hp;
    hv.x += hg0;
    hv.y += hg1;
    *hp = hv;
}

// ---------------- classifier + embedding write ----------------

__global__ __launch_bounds__(256) void k_cls(const float* __restrict__ h, const float* __restrict__ Wc,
                                             const float* __restrict__ bc,
                                             float* __restrict__ out_cls, float* __restrict__ out_emb, int n) {
    int wid = threadIdx.x >> 6;
    int lane = threadIdx.x & 63;
    int node = blockIdx.x * 4 + wid;
    if (node >= n) return;
    float h0 = h[(size_t)node * 128 + lane];
    float h1 = h[(size_t)node * 128 + 64 + lane];
    float p[10];
#pragma unroll
    for (int k = 0; k < 10; k++) p[k] = h0 * Wc[lane * 10 + k] + h1 * Wc[(64 + lane) * 10 + k];
#pragma unroll
    for (int o = 32; o; o >>= 1) {
#pragma unroll
        for (int k = 0; k < 10; k++) p[k] += __shfl_xor(p[k], o, 64);
    }
    if (lane == 0) {
#pragma unroll
        for (int k = 0; k < 10; k++) out_cls[(size_t)node * 10 + k] = p[k] + bc[k];
    }
    out_emb[(size_t)node * 128 + lane] = h0;
    out_emb[(size_t)node * 128 + 64 + lane] = h1;
}

extern "C" void kernel_launch(void* const* d_in, const int* in_sizes, int n_in,
                              void* d_out, int out_size, void* d_ws, size_t ws_size,
                              hipStream_t stream) {
    const float* x         = (const float*)d_in[0];
    const int*   edge_idx  = (const int*)d_in[1];
    const float* edge_attr = (const float*)d_in[2];
    const float* Wp        = (const float*)d_in[3];
    const float* bp        = (const float*)d_in[4];
    const float* lng       = (const float*)d_in[5];
    const float* lnb       = (const float*)d_in[6];
    const float* Wl        = (const float*)d_in[7];
    const float* bl        = (const float*)d_in[8];
    const float* Wr        = (const float*)d_in[9];
    const float* br        = (const float*)d_in[10];
    const float* We        = (const float*)d_in[11];
    const float* att       = (const float*)d_in[12];
    const float* bout      = (const float*)d_in[13];
    const float* Wc        = (const float*)d_in[14];
    const float* bc        = (const float*)d_in[15];

    const int N = N_NODES, E = N_EDGES;

    char* w = (char*)d_ws;
    size_t used = 0;
    auto take = [&](size_t bytes) -> void* {
        void* p = (void*)(w + used);
        used += (bytes + 255) & ~(size_t)255;
        return p;
    };
    float* h      = (float*)take((size_t)N * 128 * 4);
    float* xl     = (float*)take((size_t)N * 128 * 4);
    float* xr     = (float*)take((size_t)N * 128 * 4);
    int*   indeg  = (int*)take((size_t)N * 4);
    int*   offs   = (int*)take((size_t)(N + 1) * 4);
    int*   cursor = (int*)take((size_t)N * 4);
    int*   bsum   = (int*)take(64 * 4);
    int*   seid   = (int*)take((size_t)E * 4);
    int*   ssrc   = (int*)take((size_t)E * 4);
    size_t base_used = used;
    float* sea    = (float*)take((size_t)E * 16 * 4);
    bool sorted_ok = (used <= ws_size);
    (void)base_used;

    const int* srcArr = edge_idx;
    const int* dstArr = edge_idx + E;

    hipMemsetAsync(indeg, 0, (size_t)N * 4, stream);
    k_count<<<(E + 255) / 256, 256, 0, stream>>>(dstArr, indeg, E);
    int NB = (N + 1023) / 1024;
    k_scan_block<<<NB, 1024, 0, stream>>>(indeg, offs, bsum, N);
    k_scan_small<<<1, 64, 0, stream>>>(bsum, NB);
    k_scan_add<<<NB, 1024, 0, stream>>>(offs, bsum, cursor, N, E);
    k_scatter<<<(E + 255) / 256, 256, 0, stream>>>(srcArr, dstArr, cursor, seid, ssrc, E);
    if (sorted_ok)
        k_gather_ea<<<(E * 4 + 255) / 256, 256, 0, stream>>>(seid, edge_attr, sea, E);

    k_proj<<<(N + 31) / 32, 256, 0, stream>>>(x, Wp, bp, h, N);

    for (int i = 0; i < 2; i++) {
        k_ln_gemm<<<(N + 31) / 32, 256, 0, stream>>>(
            h, lng + i * 128, lnb + i * 128,
            Wl + (size_t)i * 128 * 128, bl + i * 128,
            Wr + (size_t)i * 128 * 128, br + i * 128,
            xl, xr, N);
        if (sorted_ok)
            k_gat_agg2<true><<<(N + 3) / 4, 256, 0, stream>>>(
                xl, xr, sea, offs, seid, ssrc,
                We + (size_t)i * 16 * 128, att + i * 128, bout + i * 128, h, N);
        else
            k_gat_agg2<false><<<(N + 3) / 4, 256, 0, stream>>>(
                xl, xr, edge_attr, offs, seid, ssrc,
                We + (size_t)i * 16 * 128, att + i * 128, bout + i * 128, h, N);
    }

    k_cls<<<(N + 3) / 4, 256, 0, stream>>>(h, Wc, bc, (float*)d_out, (float*)d_out + (size_t)N * KCLS, N);
}